// Round 9
// baseline (433.628 us; speedup 1.0000x reference)
//
#include <hip/hip_runtime.h>

// MMD loss, class-compacted, SINGLE persistent kernel (r9).
// r8 profile: all top-5 = harness poison fills; our 8 kernels sum ~35us but
// ~55us of inter-node gaps. Fix: one 256-block persistent kernel with manual
// grid barriers (256 blocks always co-resident: 256 <= 256 CUs, no deadlock).
// MFMA acc registers survive barriers -> dots feed both the bandwidth
// (sum of within-class <xi,xj> == ||sum x||^2) and the epilogue; this deletes
// k_colsum/k_bw and the fp32 compact array entirely.
// Math verified absmax 0.0 through r8: class bucketing, upper-tri tiles w/
// 2x off-diag, bf16 MFMA panels, C/D map col=lane&31,row=(reg&3)+8*(reg>>2)
// +4*(lane>>5).

#define CMAX 32
#define NBLK 256
#define NMAXR 6144
#define RPB 24          // NMAXR / NBLK rows per block in posgather
#define TCAP 12288

typedef __attribute__((ext_vector_type(8)))  short  short8;
typedef __attribute__((ext_vector_type(8)))  unsigned short ushort8;
typedef __attribute__((ext_vector_type(16))) float  float16;

__device__ inline unsigned short f2bf(float x) {  // fp32 -> bf16 RNE
  unsigned u = __float_as_uint(x);
  return (unsigned short)((u + 0x7FFFu + ((u >> 16) & 1u)) >> 16);
}

// Grid barrier: release fence -> arrive -> spin -> acquire fence.
// Counter monotonically increases; generation g waits for NBLK*g arrivals.
__device__ inline void gsync(int* bar, int gen) {
  __syncthreads();                      // drains block's vmem (waitcnt) too
  if (threadIdx.x == 0) {
    __threadfence();                    // device-scope release (L2 writeback)
    atomicAdd(bar, 1);
    int target = NBLK * gen;
    while (atomicAdd(bar, 0) < target) __builtin_amdgcn_s_sleep(2);
    __threadfence();                    // device-scope acquire (L2 inv)
  }
  __syncthreads();
}

__global__ __launch_bounds__(256) void k_fused(
    const float* __restrict__ src, const float* __restrict__ tgt,
    const int* __restrict__ slab, const float* __restrict__ tlabel,
    const int* __restrict__ nsd_p,
    int* cnt, int* srccnt, int* tgtcnt, float* ssum, float* dotsum,
    float* losssum, int* bar,
    int* offset, int* offpad, int* alloc, int* misc,
    int* lab, float* sq, float* sqc, float* sgnc,
    int* tileinfo, int* tileinfo2, int* tileinfo3,
    unsigned short* fragbuf, float* out,
    int S_total, int T, int D, int C) {
  __shared__ int s_tp[CMAX + 1], s_tpr[CMAX], s_off[CMAX], s_n[CMAX], s_fb[CMAX];
  __shared__ int hist[CMAX], base2[CMAX];
  __shared__ int rowpos[RPB], rowc[RPB], rowrank[RPB], rowjr[RPB], rowfb[RPB];

  int tid = threadIdx.x;
  int lane = tid & 63;
  int nsd = nsd_p[0];
  int S_use = S_total - nsd;
  int N = S_use + T;
  int gwid = (blockIdx.x * NBLK + tid) >> 6;   // global wave id (0..1023)
  int nwv = (gridDim.x * NBLK) >> 6;

  // ---------- phase 1: labels + row sq + class counts + ssum ----------
  for (int r = gwid; r < N; r += nwv) {
    int c; const float* row;
    if (r < S_use) { c = slab[nsd + r]; row = src + (size_t)(nsd + r) * D; }
    else {
      int t = r - S_use; row = tgt + (size_t)t * D;
      float v = (lane < C) ? tlabel[(size_t)t * C + lane] : -3.4e38f;
      int idx = lane;
      for (int o = 32; o > 0; o >>= 1) {
        float ov = __shfl_down(v, o, 64); int oi = __shfl_down(idx, o, 64);
        if (ov > v || (ov == v && oi < idx)) { v = ov; idx = oi; }
      }
      c = __shfl(idx, 0, 64);
    }
    const float4* r4 = (const float4*)row;
    float s = 0.f;
    for (int i = lane; i < (D >> 2); i += 64) {
      float4 q = r4[i]; s += q.x * q.x + q.y * q.y + q.z * q.z + q.w * q.w;
    }
    for (int o = 32; o > 0; o >>= 1) s += __shfl_down(s, o, 64);
    if (lane == 0) {
      sq[r] = s; lab[r] = c;
      atomicAdd(&cnt[c], 1); atomicAdd(&ssum[c], s);
      if (r < S_use) atomicAdd(&srccnt[c], 1); else atomicAdd(&tgtcnt[c], 1);
    }
  }
  gsync(bar, 1);

  // ---------- phase 2: scan + tile table (block 0 only) ----------
  if (blockIdx.x == 0) {
    if (tid == 0) {
      int o = 0, tt = 0, opad = 0;
      for (int c = 0; c < C; c++) {
        int n = atomicAdd(&cnt[c], 0);
        s_off[c] = o; s_n[c] = n; s_fb[c] = opad;
        offset[c] = o; offpad[c] = opad; alloc[c] = o;
        int tpr = (n + 31) >> 5;
        s_tpr[c] = tpr; s_tp[c] = tt;
        o += n; tt += tpr * (tpr + 1) / 2; opad += tpr * 32;
      }
      s_tp[C] = tt; misc[0] = tt; misc[1] = o;
    }
    __syncthreads();
    int tt = s_tp[C];
    for (int t = tid; t < tt && t < TCAP; t += NBLK) {
      int c = 0;
      while (t >= s_tp[c + 1]) c++;
      int lt = t - s_tp[c], tpr = s_tpr[c], jt = 0;
      while (lt >= tpr - jt) { lt -= tpr - jt; jt++; }
      int kt = jt + lt;
      tileinfo[t] = c | (jt << 8) | (kt << 16);
      tileinfo2[t] = s_off[c] | (s_n[c] << 16);
      tileinfo3[t] = s_fb[c];
    }
  }
  gsync(bar, 2);

  // ---------- phase 3: positions + gather bf16 fragment panels ----------
  {
    int r0 = blockIdx.x * RPB;
    if (tid < CMAX) hist[tid] = 0;
    __syncthreads();
    if (tid < RPB) {
      int r = r0 + tid;
      if (r < N) { int c = lab[r]; rowc[tid] = c; rowrank[tid] = atomicAdd(&hist[c], 1); }
    }
    __syncthreads();
    if (tid < C && hist[tid] > 0) base2[tid] = atomicAdd(&alloc[tid], hist[tid]);
    __syncthreads();
    if (tid < RPB) {
      int r = r0 + tid;
      if (r < N) {
        int c = rowc[tid];
        int p = base2[c] + rowrank[tid];
        rowpos[tid] = p; rowjr[tid] = p - offset[c]; rowfb[tid] = offpad[c];
        sqc[p] = sq[r]; sgnc[p] = (r < S_use) ? 1.f : -1.f;
      }
    }
    __syncthreads();
    for (int rr = tid >> 6; rr < RPB; rr += 4) {   // wave per row
      int r = r0 + rr;
      if (r >= N) break;
      int jr = rowjr[rr], fb = rowfb[rr];
      const float* row = (r < S_use) ? src + (size_t)(nsd + r) * D
                                     : tgt + (size_t)(r - S_use) * D;
      const float4* s4 = (const float4*)row;
      unsigned short* pb = fragbuf + (size_t)(fb + (jr & ~31)) * D;
      int row32 = jr & 31;
      for (int m = lane; m < (D >> 3); m += 64) {  // chunk m: cols m*8..m*8+7
        float4 v0 = s4[m * 2], v1 = s4[m * 2 + 1];
        ushort8 h;
        h[0] = f2bf(v0.x); h[1] = f2bf(v0.y); h[2] = f2bf(v0.z); h[3] = f2bf(v0.w);
        h[4] = f2bf(v1.x); h[5] = f2bf(v1.y); h[6] = f2bf(v1.z); h[7] = f2bf(v1.w);
        int s = m >> 1, hf = m & 1;
        *(ushort8*)(pb + s * 512 + (hf * 32 + row32) * 8) = h;
      }
    }
  }
  gsync(bar, 3);

  // ---------- phase 4: MFMA dots (+ masked per-class dot-sum for bw) ----------
  int tileTotal = misc[0];
  int l31 = lane & 31, half = lane >> 5;
  float16 acc0 = {};                 // first tile's dots survive the barrier
  for (int t = gwid; t < tileTotal; t += nwv) {
    int info = tileinfo[t];
    int c = info & 255, jt = (info >> 8) & 255, kt = (info >> 16) & 255;
    int n = ((unsigned)tileinfo2[t]) >> 16;
    int fb = tileinfo3[t];
    int jbase = jt << 5, kbase = kt << 5;
    float wgt = (jt == kt) ? 1.f : 2.f;
    const unsigned short* fa  = fragbuf + (size_t)(fb + jbase) * D + lane * 8;
    const unsigned short* fbp = fragbuf + (size_t)(fb + kbase) * D + lane * 8;
    float16 acc = {};
    if (D == 512) {
      #pragma unroll
      for (int s = 0; s < 32; s++) {
        short8 a = *(const short8*)(fa + s * 512);
        short8 b = *(const short8*)(fbp + s * 512);
        acc = __builtin_amdgcn_mfma_f32_32x32x16_bf16(a, b, acc, 0, 0, 0);
      }
    } else {
      for (int s = 0; s < (D >> 4); s++) {
        short8 a = *(const short8*)(fa + s * 512);
        short8 b = *(const short8*)(fbp + s * 512);
        acc = __builtin_amdgcn_mfma_f32_32x32x16_bf16(a, b, acc, 0, 0, 0);
      }
    }
    float msum = 0.f;                       // masked sum of dots -> ||sum x||^2
    bool kval = (kbase + l31) < n;
    #pragma unroll
    for (int r = 0; r < 16; r++) {
      int m = (r & 3) + 8 * (r >> 2) + 4 * half;
      if (kval && (jbase + m) < n) msum += acc[r];
    }
    msum *= wgt;
    for (int o = 32; o > 0; o >>= 1) msum += __shfl_down(msum, o, 64);
    if (lane == 0) atomicAdd(&dotsum[c], msum);
    if (t == gwid) acc0 = acc;
  }
  gsync(bar, 4);

  // ---------- phase 5: epilogue (bw inline), per-class loss ----------
  for (int t = gwid; t < tileTotal; t += nwv) {
    int info = tileinfo[t];
    int c = info & 255, jt = (info >> 8) & 255, kt = (info >> 16) & 255;
    int info2 = tileinfo2[t];
    int off = info2 & 0xFFFF;
    int n = ((unsigned)info2) >> 16;
    int fb = tileinfo3[t];
    int jbase = jt << 5, kbase = kt << 5;
    float wgt = (jt == kt) ? 1.f : 2.f;
    float16 acc;
    if (t == gwid) acc = acc0;
    else {  // >1024 tiles fallback: recompute (not hit for actual shapes)
      const unsigned short* fa  = fragbuf + (size_t)(fb + jbase) * D + lane * 8;
      const unsigned short* fbp = fragbuf + (size_t)(fb + kbase) * D + lane * 8;
      float16 a2 = {};
      for (int s = 0; s < (D >> 4); s++) {
        short8 a = *(const short8*)(fa + s * 512);
        short8 b = *(const short8*)(fbp + s * 512);
        a2 = __builtin_amdgcn_mfma_f32_32x32x16_bf16(a, b, a2, 0, 0, 0);
      }
      acc = a2;
    }
    float nf = (float)n;
    float ds = atomicAdd(&dotsum[c], 0.f);
    float ss = atomicAdd(&ssum[c], 0.f);
    float S1 = 2.f * nf * ss - 2.f * ds;    // == m @ Dmat @ m
    float bw = S1 / fmaxf(nf * nf - nf, 1.f);
    bw = (bw > 0.f) ? bw : 1.f;
    float inv0 = 4.f / bw;                  // 1 / (bw * 0.25)
    float sqk = sqc[off + kbase + l31];
    float sgk = sgnc[off + kbase + l31];
    bool kval = (kbase + l31) < n;
    float sqjv = sqc[off + jbase + l31];
    float sgjv = sgnc[off + jbase + l31];
    float contrib = 0.f;
    #pragma unroll
    for (int r = 0; r < 16; r++) {
      int m = (r & 3) + 8 * (r >> 2) + 4 * half;
      float sqj = __shfl(sqjv, m, 64);
      float sgj = __shfl(sgjv, m, 64);
      if (kval && (jbase + m) < n) {
        float d = fmaxf(sqj + sqk - 2.f * acc[r], 0.f);
        float s = inv0, kv = 0.f;
        #pragma unroll
        for (int q = 0; q < 5; q++) { kv += __expf(-d * s); s *= 0.5f; }
        contrib += sgj * sgk * kv;
      }
    }
    contrib *= wgt;
    for (int o = 32; o > 0; o >>= 1) contrib += __shfl_down(contrib, o, 64);
    if (lane == 0) atomicAdd(&losssum[c], contrib);
  }
  gsync(bar, 5);

  // ---------- phase 6: final scalar (block 0, lane per class) ----------
  if (blockIdx.x == 0 && tid < 64) {
    int c = tid;
    float loss = 0.f, cv = 0.f;
    if (c < C) {
      int sc = atomicAdd(&srccnt[c], 0), tc = atomicAdd(&tgtcnt[c], 0);
      if (sc > 0 && tc > 0) {
        float nf = (float)atomicAdd(&cnt[c], 0);
        loss = atomicAdd(&losssum[c], 0.f) / fmaxf(nf * nf, 1.f);
        cv = 1.f;
      }
    }
    for (int o = 32; o > 0; o >>= 1) {
      loss += __shfl_down(loss, o, 64);
      cv   += __shfl_down(cv, o, 64);
    }
    if (tid == 0) out[0] = loss / fmaxf(cv, 1.f);
  }
}

extern "C" void kernel_launch(void* const* d_in, const int* in_sizes, int n_in,
                              void* d_out, int out_size, void* d_ws, size_t ws_size,
                              hipStream_t stream) {
  const float* source = (const float*)d_in[0];
  const float* target = (const float*)d_in[1];
  const int* slab     = (const int*)d_in[2];
  const float* tlabel = (const float*)d_in[3];
  const int* nsd_p    = (const int*)d_in[4];
  float* out = (float*)d_out;

  int S_total = in_sizes[2];
  int D = in_sizes[0] / S_total;   // 512
  int T = in_sizes[1] / D;         // 2048
  int C = in_sizes[3] / T;         // 31
  int NMAX = S_total + T;          // 6144 upper bound; actual N read on device
  int NMAXP = NMAX + 32 * CMAX;    // padded panel capacity (7168 rows)

  // workspace layout (4-byte words); zeroed region first
  int* ws = (int*)d_ws;
  int* cnt      = ws;                     // C
  int* srccnt   = cnt + C;                // C
  int* tgtcnt   = srccnt + C;             // C
  float* ssum   = (float*)(tgtcnt + C);   // C
  float* dotsum = ssum + C;               // C
  float* losssum = dotsum + C;            // C
  int* bar      = (int*)(losssum + C);    // 8 (counter + pad)
  int zwords    = 6 * C + 8;              // all zeroed by memset

  int* offset   = bar + 8;                // C
  int* offpad   = offset + C;             // C
  int* alloc    = offpad + C;             // C
  int* misc     = alloc + C;              // 2
  int* lab      = misc + 2;               // NMAX
  float* sq     = (float*)(lab + NMAX);   // NMAX
  float* sqc    = sq + NMAX;              // NMAX
  float* sgnc   = sqc + NMAX;             // NMAX
  int* tileinfo = (int*)(sgnc + NMAX);    // TCAP
  int* tileinfo2 = tileinfo + TCAP;       // TCAP
  int* tileinfo3 = tileinfo2 + TCAP;      // TCAP
  size_t words_used = (size_t)zwords + (3 * C + 2) + 4 * NMAX + 3 * TCAP;
  size_t fw = (words_used + 63) & ~(size_t)63;   // 256B-align fragbuf
  unsigned short* fragbuf = (unsigned short*)(ws + fw);  // NMAXP * D bf16

  (void)NMAXP; (void)ws_size;

  hipMemsetAsync(d_ws, 0, (size_t)zwords * sizeof(int), stream);

  k_fused<<<NBLK, 256, 0, stream>>>(source, target, slab, tlabel, nsd_p,
                                    cnt, srccnt, tgtcnt, ssum, dotsum,
                                    losssum, bar,
                                    offset, offpad, alloc, misc,
                                    lab, sq, sqc, sgnc,
                                    tileinfo, tileinfo2, tileinfo3,
                                    fragbuf, out,
                                    S_total, T, D, C);
}

// Round 10
// 143.467 us; speedup vs baseline: 3.0225x; 3.0225x over previous
//
#include <hip/hip_runtime.h>

// MMD loss, class-compacted (r10). Multi-kernel (r8 base, 141us) with node
// count cut 9 -> 5: k_scan deleted (per-block redundant LDS prefix over 31
// classes), k_bw deleted (inline ||sum x||^2 per tile from colsum), k_final
// deleted (last-block-done fold in k_pairs), fp32 compact deleted (colsum
// reads bf16 panels). r9's persistent grid-barrier design REGRESSED to 434us
// (256 blocks spin-polling one line with device atomics ~70us/barrier) - do
// not reintroduce. Math verified absmax 0.0 r1-r9: bucketing, upper-tri
// tiles w/ 2x off-diag, identity m@D@m = 2n*sum(sq)-2*||sum x||^2, MFMA C/D
// map col=lane&31, row=(reg&3)+8*(reg>>2)+4*(lane>>5).

#define CMAX 32
#define RCHUNK 16

typedef __attribute__((ext_vector_type(8)))  short  short8;
typedef __attribute__((ext_vector_type(8)))  unsigned short ushort8;
typedef __attribute__((ext_vector_type(16))) float  float16;

__device__ inline unsigned short f2bf(float x) {  // fp32 -> bf16 RNE
  unsigned u = __float_as_uint(x);
  return (unsigned short)((u + 0x7FFFu + ((u >> 16) & 1u)) >> 16);
}

// ---- K1: labels + row sq + class counts + ssum; also zeroes colsum ----
__global__ __launch_bounds__(256) void k_prep(
    const float* __restrict__ src, const float* __restrict__ tgt,
    const int* __restrict__ slab, const float* __restrict__ tlabel,
    const int* __restrict__ nsd_p,
    int* __restrict__ lab, float* __restrict__ sq,
    int* cnt, int* srccnt, int* tgtcnt, float* ssum, float* colsum,
    int S_total, int T, int D, int C) {
  // zero colsum (read only by later kernels; no sync needed)
  for (int i = blockIdx.x * 256 + threadIdx.x; i < C * D; i += gridDim.x * 256)
    colsum[i] = 0.f;

  int nsd = nsd_p[0];
  int S_use = S_total - nsd;
  int N = S_use + T;
  int lane = threadIdx.x & 63;
  int wid = (blockIdx.x * 256 + threadIdx.x) >> 6;
  int nw = (gridDim.x * 256) >> 6;
  for (int r = wid; r < N; r += nw) {
    int c; const float* row;
    if (r < S_use) {
      c = slab[nsd + r];
      row = src + (size_t)(nsd + r) * D;
    } else {
      int t = r - S_use;
      row = tgt + (size_t)t * D;
      float v = (lane < C) ? tlabel[(size_t)t * C + lane] : -3.4e38f;
      int idx = lane;
      for (int o = 32; o > 0; o >>= 1) {
        float ov = __shfl_down(v, o, 64);
        int oi = __shfl_down(idx, o, 64);
        if (ov > v || (ov == v && oi < idx)) { v = ov; idx = oi; }
      }
      c = __shfl(idx, 0, 64);
    }
    const float4* r4 = (const float4*)row;
    float s = 0.f;
    for (int i = lane; i < (D >> 2); i += 64) {
      float4 q = r4[i];
      s += q.x * q.x + q.y * q.y + q.z * q.z + q.w * q.w;
    }
    for (int o = 32; o > 0; o >>= 1) s += __shfl_down(s, o, 64);
    if (lane == 0) {
      sq[r] = s; lab[r] = c;
      atomicAdd(&cnt[c], 1);
      atomicAdd(&ssum[c], s);
      if (r < S_use) atomicAdd(&srccnt[c], 1); else atomicAdd(&tgtcnt[c], 1);
    }
  }
}

// ---- K2: positions (redundant LDS prefix + zero-based chunk alloc) +
//          gather bf16 MFMA-fragment panels + sqc/sgnc ----
// Panel layout per class: 32-row panels at (fb + (jr&~31))*D shorts; K-step s
// holds chunk m=2s+hf (cols m*8..m*8+7) of row jr at s*512+(hf*32+(jr&31))*8.
__global__ __launch_bounds__(256) void k_posgather(
    const float* __restrict__ src, const float* __restrict__ tgt,
    const int* __restrict__ nsd_p, const int* __restrict__ lab,
    const float* __restrict__ sq, const int* __restrict__ cnt, int* alloc,
    unsigned short* __restrict__ fragbuf,
    float* __restrict__ sqc, float* __restrict__ sgnc,
    int S_total, int T, int D, int C) {
  __shared__ int s_off[CMAX], s_fb[CMAX];
  __shared__ int hist[CMAX], base2[CMAX];
  __shared__ int rowc[64], rowrank[64], rowjr[64], rowfb[64];
  int tid = threadIdx.x;
  if (tid < CMAX) hist[tid] = 0;
  __syncthreads();
  if (tid == 0) {          // redundant per-block exclusive scan (31 iters, LDS-fast)
    int o = 0, opad = 0;
    for (int c = 0; c < C; c++) {
      s_off[c] = o; s_fb[c] = opad;
      int n = cnt[c];
      o += n; opad += ((n + 31) >> 5) << 5;
    }
  }
  __syncthreads();
  int nsd = nsd_p[0];
  int S_use = S_total - nsd;
  int N = S_use + T;
  int r0 = blockIdx.x * 64;
  if (tid < 64) {
    int r = r0 + tid;
    if (r < N) { int c = lab[r]; rowc[tid] = c; rowrank[tid] = atomicAdd(&hist[c], 1); }
  }
  __syncthreads();
  if (tid < C && hist[tid] > 0) base2[tid] = atomicAdd(&alloc[tid], hist[tid]);
  __syncthreads();
  if (tid < 64) {
    int r = r0 + tid;
    if (r < N) {
      int c = rowc[tid];
      int jr = base2[c] + rowrank[tid];      // row index within class
      int p = s_off[c] + jr;                 // compacted global index
      rowjr[tid] = jr; rowfb[tid] = s_fb[c];
      sqc[p] = sq[r];
      sgnc[p] = (r < S_use) ? 1.f : -1.f;
    }
  }
  __syncthreads();
  int lane = tid & 63;
  for (int rr = tid >> 6; rr < 64; rr += 4) {   // wave per row
    int r = r0 + rr;
    if (r >= N) break;
    int jr = rowjr[rr], fb = rowfb[rr];
    const float* row = (r < S_use) ? src + (size_t)(nsd + r) * D
                                   : tgt + (size_t)(r - S_use) * D;
    const float4* s4 = (const float4*)row;
    unsigned short* pb = fragbuf + (size_t)(fb + (jr & ~31)) * D;
    int row32 = jr & 31;
    for (int m = lane; m < (D >> 3); m += 64) {
      float4 v0 = s4[m * 2], v1 = s4[m * 2 + 1];
      ushort8 h;
      h[0] = f2bf(v0.x); h[1] = f2bf(v0.y); h[2] = f2bf(v0.z); h[3] = f2bf(v0.w);
      h[4] = f2bf(v1.x); h[5] = f2bf(v1.y); h[6] = f2bf(v1.z); h[7] = f2bf(v1.w);
      int s = m >> 1, hf = m & 1;
      *(ushort8*)(pb + s * 512 + (hf * 32 + row32) * 8) = h;
    }
  }
}

// ---- K3: per-class column sums from bf16 panels (row-chunk parallel) ----
__global__ __launch_bounds__(256) void k_colsum(
    const unsigned short* __restrict__ fragbuf, const int* __restrict__ cnt,
    float* __restrict__ colsum, int D, int C) {
  __shared__ int s_fb[CMAX];
  int tid = threadIdx.x;
  if (tid == 0) {
    int opad = 0;
    for (int c = 0; c < C; c++) { s_fb[c] = opad; opad += ((cnt[c] + 31) >> 5) << 5; }
  }
  __syncthreads();
  int c = blockIdx.x;
  int n = cnt[c], fb = s_fb[c];
  int i0 = (int)(((long long)n * blockIdx.y) / gridDim.y);
  int i1 = (int)(((long long)n * (blockIdx.y + 1)) / gridDim.y);
  for (int d = tid; d < D; d += 256) {
    int s = d >> 4, hf = (d >> 3) & 1, e = d & 7;
    int colbase = s * 512 + hf * 256 + e;
    float sum = 0.f;
    for (int i = i0; i < i1; i++) {
      unsigned short v = fragbuf[(size_t)(fb + (i & ~31)) * D + colbase + (i & 31) * 8];
      sum += __uint_as_float((unsigned)v << 16);
    }
    if (sum != 0.f) atomicAdd(&colsum[(size_t)c * D + d], sum);
  }
}

// ---- K4: MFMA pair tiles + inline bw + last-block final fold ----
__global__ __launch_bounds__(256) void k_pairs(
    const unsigned short* __restrict__ fragbuf, const float* __restrict__ sqc,
    const float* __restrict__ sgnc, const int* __restrict__ cnt,
    const int* __restrict__ srccnt, const int* __restrict__ tgtcnt,
    const float* __restrict__ ssum, const float* __restrict__ colsum,
    float* losssum, int* done, float* __restrict__ out, int D, int C) {
  __shared__ int s_tp[CMAX + 1], s_tpr[CMAX], s_off[CMAX], s_n[CMAX], s_fb[CMAX];
  __shared__ int lastFlag;
  int tid = threadIdx.x;
  if (tid == 0) {          // redundant per-block scan + tile prefix
    int o = 0, tt = 0, opad = 0;
    for (int c = 0; c < C; c++) {
      int n = cnt[c];
      s_off[c] = o; s_n[c] = n; s_fb[c] = opad; s_tp[c] = tt;
      int tpr = (n + 31) >> 5;
      s_tpr[c] = tpr;
      o += n; tt += tpr * (tpr + 1) / 2; opad += tpr * 32;
    }
    s_tp[C] = tt;
  }
  __syncthreads();
  int tileTotal = s_tp[C];
  int lane = tid & 63;
  int l31 = lane & 31, half = lane >> 5;
  int wv = blockIdx.x * 4 + (tid >> 6);
  int nwv = gridDim.x * 4;

  for (int t = wv; t < tileTotal; t += nwv) {
    int c = 0;
    while (t >= s_tp[c + 1]) c++;
    int lt = t - s_tp[c], tpr = s_tpr[c], jt = 0;
    while (lt >= tpr - jt) { lt -= tpr - jt; jt++; }
    int kt = jt + lt;
    int off = s_off[c], n = s_n[c], fb = s_fb[c];
    int jbase = jt << 5, kbase = kt << 5;
    float wgt = (jt == kt) ? 1.f : 2.f;

    const unsigned short* fa  = fragbuf + (size_t)(fb + jbase) * D + lane * 8;
    const unsigned short* fbp = fragbuf + (size_t)(fb + kbase) * D + lane * 8;
    float16 acc = {};
    if (D == 512) {
      #pragma unroll
      for (int s = 0; s < 32; s++) {
        short8 a = *(const short8*)(fa + s * 512);
        short8 b = *(const short8*)(fbp + s * 512);
        acc = __builtin_amdgcn_mfma_f32_32x32x16_bf16(a, b, acc, 0, 0, 0);
      }
    } else {
      for (int s = 0; s < (D >> 4); s++) {
        short8 a = *(const short8*)(fa + s * 512);
        short8 b = *(const short8*)(fbp + s * 512);
        acc = __builtin_amdgcn_mfma_f32_32x32x16_bf16(a, b, acc, 0, 0, 0);
      }
    }

    // inline bandwidth: ns = ||sum x||^2 from colsum (butterfly -> all lanes)
    float ns = 0.f;
    for (int d = lane * 8; d < D; d += 512) {
      float4 u0 = *(const float4*)(colsum + (size_t)c * D + d);
      float4 u1 = *(const float4*)(colsum + (size_t)c * D + d + 4);
      ns += u0.x * u0.x + u0.y * u0.y + u0.z * u0.z + u0.w * u0.w +
            u1.x * u1.x + u1.y * u1.y + u1.z * u1.z + u1.w * u1.w;
    }
    for (int o = 32; o > 0; o >>= 1) ns += __shfl_xor(ns, o, 64);
    float nf = (float)n;
    float S1 = 2.f * nf * ssum[c] - 2.f * ns;   // == m @ Dmat @ m
    float bw = S1 / fmaxf(nf * nf - nf, 1.f);
    bw = (bw > 0.f) ? bw : 1.f;
    float inv0 = 4.f / bw;                      // 1 / (bw * 0.25)

    float sqk = sqc[off + kbase + l31];
    float sgk = sgnc[off + kbase + l31];
    bool kval = (kbase + l31) < n;
    float sqjv = sqc[off + jbase + l31];
    float sgjv = sgnc[off + jbase + l31];
    float contrib = 0.f;
    #pragma unroll
    for (int r = 0; r < 16; r++) {
      int m = (r & 3) + 8 * (r >> 2) + 4 * half;
      float sqj = __shfl(sqjv, m, 64);
      float sgj = __shfl(sgjv, m, 64);
      if (kval && (jbase + m) < n) {
        float d = fmaxf(sqj + sqk - 2.f * acc[r], 0.f);
        float s = inv0, kv = 0.f;
        #pragma unroll
        for (int q = 0; q < 5; q++) { kv += __expf(-d * s); s *= 0.5f; }
        contrib += sgj * sgk * kv;
      }
    }
    contrib *= wgt;
    for (int o = 32; o > 0; o >>= 1) contrib += __shfl_down(contrib, o, 64);
    if (lane == 0) atomicAdd(&losssum[c], contrib);
  }

  // last-block fold -> final scalar (one fence+atomic per BLOCK: 208 total)
  __syncthreads();
  if (tid == 0) {
    __threadfence();
    int d = atomicAdd(done, 1);
    lastFlag = (d == (int)gridDim.x - 1);
  }
  __syncthreads();
  if (lastFlag && tid < 64) {
    int c = tid;
    float loss = 0.f, cv = 0.f;
    if (c < C && srccnt[c] > 0 && tgtcnt[c] > 0) {
      float nf = (float)cnt[c];
      loss = atomicAdd(&losssum[c], 0.f) / fmaxf(nf * nf, 1.f);  // coherent read
      cv = 1.f;
    }
    for (int o = 32; o > 0; o >>= 1) {
      loss += __shfl_down(loss, o, 64);
      cv   += __shfl_down(cv, o, 64);
    }
    if (tid == 0) out[0] = loss / fmaxf(cv, 1.f);
  }
}

extern "C" void kernel_launch(void* const* d_in, const int* in_sizes, int n_in,
                              void* d_out, int out_size, void* d_ws, size_t ws_size,
                              hipStream_t stream) {
  const float* source = (const float*)d_in[0];
  const float* target = (const float*)d_in[1];
  const int* slab     = (const int*)d_in[2];
  const float* tlabel = (const float*)d_in[3];
  const int* nsd_p    = (const int*)d_in[4];
  float* out = (float*)d_out;

  int S_total = in_sizes[2];
  int D = in_sizes[0] / S_total;   // 512
  int T = in_sizes[1] / D;         // 2048
  int C = in_sizes[3] / T;         // 31
  int NMAX = S_total + T;          // 6144 upper bound; actual N read on device

  // workspace layout (4-byte words); zeroed-by-memset region first (tiny)
  int* ws = (int*)d_ws;
  int* cnt      = ws;                     // C
  int* srccnt   = cnt + C;                // C
  int* tgtcnt   = srccnt + C;             // C
  float* ssum   = (float*)(tgtcnt + C);   // C
  float* losssum = ssum + C;              // C
  int* alloc    = (int*)(losssum + C);    // C
  int* done     = alloc + C;              // 8 (counter + pad)
  int zwords    = 6 * C + 8;

  float* colsum = (float*)(done + 8);     // C*D (zeroed by k_prep)
  int* lab      = (int*)(colsum + (size_t)C * D);  // NMAX
  float* sq     = (float*)(lab + NMAX);   // NMAX
  float* sqc    = sq + NMAX;              // NMAX
  float* sgnc   = sqc + NMAX;             // NMAX
  size_t words_used = (size_t)zwords + C * D + 4 * NMAX;
  size_t fw = (words_used + 63) & ~(size_t)63;   // 256B-align fragbuf
  unsigned short* fragbuf = (unsigned short*)(ws + fw);  // (NMAX+32*CMAX)*D bf16

  hipMemsetAsync(d_ws, 0, (size_t)zwords * sizeof(int), stream);

  k_prep<<<768, 256, 0, stream>>>(source, target, slab, tlabel, nsd_p,
                                  lab, sq, cnt, srccnt, tgtcnt, ssum, colsum,
                                  S_total, T, D, C);
  k_posgather<<<NMAX / 64, 256, 0, stream>>>(source, target, nsd_p, lab, sq,
                                             cnt, alloc, fragbuf, sqc, sgnc,
                                             S_total, T, D, C);
  k_colsum<<<dim3(C, RCHUNK), 256, 0, stream>>>(fragbuf, cnt, colsum, D, C);
  k_pairs<<<208, 256, 0, stream>>>(fragbuf, sqc, sgnc, cnt, srccnt, tgtcnt,
                                   ssum, colsum, losssum, done, out, D, C);
}

// Round 11
// 124.603 us; speedup vs baseline: 3.4801x; 1.1514x over previous
//
#include <hip/hip_runtime.h>

// MMD loss, class-compacted (r11). 4 nodes: memset, k_fused (label+sq+rank+
// bf16 panel gather, ONE input pass), k_colsum, k_pairs(+fold).
// Key r11 change: fixed per-class capacity CAP -> row destination p=c*CAP+rank
// needs no global prefix scan; k_prep deleted; offsets are constants.
// DO NOT reintroduce: r9 persistent grid-barrier (434us, spin atomics);
// r5 per-element colsum atomics (34MB HBM writes); r2 per-block fences at
// 6144 grid (141us). Math verified absmax 0.0 r1-r10: class bucketing,
// upper-tri tiles w/ 2x off-diag, m@D@m = 2n*sum(sq)-2*||sum x||^2,
// MFMA C/D map col=lane&31, row=(reg&3)+8*(reg>>2)+4*(lane>>5).

#define CMAX 32
#define RCAP 6144      // fixed rows per class region
#define RCHUNK 16

typedef __attribute__((ext_vector_type(8)))  short  short8;
typedef __attribute__((ext_vector_type(8)))  unsigned short ushort8;
typedef __attribute__((ext_vector_type(16))) float  float16;

__device__ inline unsigned short f2bf(float x) {  // fp32 -> bf16 RNE
  unsigned u = __float_as_uint(x);
  return (unsigned short)((u + 0x7FFFu + ((u >> 16) & 1u)) >> 16);
}

// ---- K1: single-pass label + rank + sq + bf16 MFMA-fragment panels ----
// Panel layout for class c: base c*RCAP rows; 32-row panels; K-step s holds
// chunk m=2s+hf (cols m*8..m*8+7) of row jr at panel*D + s*512+(hf*32+(jr&31))*8.
__global__ __launch_bounds__(256) void k_fused(
    const float* __restrict__ src, const float* __restrict__ tgt,
    const int* __restrict__ slab, const float* __restrict__ tlabel,
    const int* __restrict__ nsd_p,
    int* alloc, int* srccnt, int* tgtcnt, float* ssum,
    unsigned short* __restrict__ fragbuf,
    float* __restrict__ sqc, float* __restrict__ sgnc,
    int S_total, int T, int D, int C) {
  __shared__ int hist[CMAX], hsrc[CMAX], htgt[CMAX], base2[CMAX];
  __shared__ float lssum[CMAX];
  __shared__ int rowc[64], rowp[64];
  int tid = threadIdx.x;
  int lane = tid & 63;
  int w = tid >> 6;
  if (tid < CMAX) { hist[tid] = 0; hsrc[tid] = 0; htgt[tid] = 0; lssum[tid] = 0.f; }
  __syncthreads();

  int nsd = nsd_p[0];
  int S_use = S_total - nsd;
  int N = S_use + T;
  int r0 = blockIdx.x * 64;

  // phase A: labels (wave per row; argmax for target rows)
  for (int rr = w * 16; rr < w * 16 + 16; rr++) {
    int r = r0 + rr;
    if (r >= N) break;
    int c;
    if (r < S_use) {
      c = slab[nsd + r];
    } else {
      int t = r - S_use;
      float v = (lane < C) ? tlabel[(size_t)t * C + lane] : -3.4e38f;
      int idx = lane;
      for (int o = 32; o > 0; o >>= 1) {
        float ov = __shfl_down(v, o, 64);
        int oi = __shfl_down(idx, o, 64);
        if (ov > v || (ov == v && oi < idx)) { v = ov; idx = oi; }
      }
      c = __shfl(idx, 0, 64);
    }
    if (lane == 0) rowc[rr] = c;
  }
  __syncthreads();

  // phase B: LDS rank + per-block chunk alloc (31 global atomics per block)
  if (tid < 64) {
    int r = r0 + tid;
    if (r < N) {
      int c = rowc[tid];
      int rk = atomicAdd(&hist[c], 1);
      rowp[tid] = rk;  // temp: rank
      if (r < S_use) atomicAdd(&hsrc[c], 1); else atomicAdd(&htgt[c], 1);
    }
  }
  __syncthreads();
  if (tid < C && hist[tid] > 0) base2[tid] = atomicAdd(&alloc[tid], hist[tid]);
  __syncthreads();
  if (tid < 64) {
    int r = r0 + tid;
    if (r < N) rowp[tid] = rowc[tid] * RCAP + base2[rowc[tid]] + rowp[tid];
  }
  __syncthreads();

  // phase C: wave per row — read once: sq + bf16 convert + panel write
  for (int rr = w * 16; rr < w * 16 + 16; rr++) {
    int r = r0 + rr;
    if (r >= N) break;
    int p = rowp[rr];
    int c = rowc[rr];
    int jr = p - c * RCAP;
    const float* row = (r < S_use) ? src + (size_t)(nsd + r) * D
                                   : tgt + (size_t)(r - S_use) * D;
    const float4* s4 = (const float4*)row;
    unsigned short* pb = fragbuf + (size_t)(c * RCAP + (jr & ~31)) * D;
    int row32 = jr & 31;
    float s = 0.f;
    for (int m = lane; m < (D >> 3); m += 64) {
      float4 v0 = s4[m * 2], v1 = s4[m * 2 + 1];
      s += v0.x * v0.x + v0.y * v0.y + v0.z * v0.z + v0.w * v0.w +
           v1.x * v1.x + v1.y * v1.y + v1.z * v1.z + v1.w * v1.w;
      ushort8 h;
      h[0] = f2bf(v0.x); h[1] = f2bf(v0.y); h[2] = f2bf(v0.z); h[3] = f2bf(v0.w);
      h[4] = f2bf(v1.x); h[5] = f2bf(v1.y); h[6] = f2bf(v1.z); h[7] = f2bf(v1.w);
      int st = m >> 1, hf = m & 1;
      *(ushort8*)(pb + st * 512 + (hf * 32 + row32) * 8) = h;
    }
    for (int o = 32; o > 0; o >>= 1) s += __shfl_down(s, o, 64);
    if (lane == 0) {
      sqc[p] = s;
      sgnc[p] = (r < S_use) ? 1.f : -1.f;
      atomicAdd(&lssum[c], s);
    }
  }
  __syncthreads();
  if (tid < C) {
    if (lssum[tid] != 0.f) atomicAdd(&ssum[tid], lssum[tid]);
    if (hsrc[tid]) atomicAdd(&srccnt[tid], hsrc[tid]);
    if (htgt[tid]) atomicAdd(&tgtcnt[tid], htgt[tid]);
  }
}

// ---- K2: per-class column sums from bf16 panels (row-chunk parallel) ----
__global__ __launch_bounds__(256) void k_colsum(
    const unsigned short* __restrict__ fragbuf, const int* __restrict__ cnt,
    float* __restrict__ colsum, int D) {
  int c = blockIdx.x;
  int n = cnt[c];
  int i0 = (int)(((long long)n * blockIdx.y) / gridDim.y);
  int i1 = (int)(((long long)n * (blockIdx.y + 1)) / gridDim.y);
  int tid = threadIdx.x;
  const unsigned short* base = fragbuf + (size_t)c * RCAP * D;
  for (int d = tid; d < D; d += 256) {
    int s = d >> 4, hf = (d >> 3) & 1, e = d & 7;
    int colbase = s * 512 + hf * 256 + e;
    float sum = 0.f;
    for (int i = i0; i < i1; i++) {
      unsigned short v = base[(size_t)(i & ~31) * D + colbase + (i & 31) * 8];
      sum += __uint_as_float((unsigned)v << 16);
    }
    if (sum != 0.f) atomicAdd(&colsum[(size_t)c * D + d], sum);
  }
}

// ---- K3: MFMA pair tiles + inline bw + last-block final fold ----
__global__ __launch_bounds__(256) void k_pairs(
    const unsigned short* __restrict__ fragbuf, const float* __restrict__ sqc,
    const float* __restrict__ sgnc, const int* __restrict__ cnt,
    const int* __restrict__ srccnt, const int* __restrict__ tgtcnt,
    const float* __restrict__ ssum, const float* __restrict__ colsum,
    float* losssum, int* done, float* __restrict__ out, int D, int C) {
  __shared__ int s_tp[CMAX + 1], s_tpr[CMAX], s_n[CMAX];
  __shared__ int lastFlag;
  int tid = threadIdx.x;
  if (tid == 0) {          // redundant per-block tile prefix (31 iters, LDS)
    int tt = 0;
    for (int c = 0; c < C; c++) {
      int n = cnt[c];
      s_n[c] = n; s_tp[c] = tt;
      int tpr = (n + 31) >> 5;
      s_tpr[c] = tpr;
      tt += tpr * (tpr + 1) / 2;
    }
    s_tp[C] = tt;
  }
  __syncthreads();
  int tileTotal = s_tp[C];
  int lane = tid & 63;
  int l31 = lane & 31, half = lane >> 5;
  int wv = blockIdx.x * 4 + (tid >> 6);
  int nwv = gridDim.x * 4;

  for (int t = wv; t < tileTotal; t += nwv) {
    int c = 0;
    while (t >= s_tp[c + 1]) c++;
    int lt = t - s_tp[c], tpr = s_tpr[c], jt = 0;
    while (lt >= tpr - jt) { lt -= tpr - jt; jt++; }
    int kt = jt + lt;
    int n = s_n[c];
    int off = c * RCAP;
    int jbase = jt << 5, kbase = kt << 5;
    float wgt = (jt == kt) ? 1.f : 2.f;

    const unsigned short* fa  = fragbuf + (size_t)(off + jbase) * D + lane * 8;
    const unsigned short* fbp = fragbuf + (size_t)(off + kbase) * D + lane * 8;
    float16 acc = {};
    if (D == 512) {
      #pragma unroll
      for (int s = 0; s < 32; s++) {
        short8 a = *(const short8*)(fa + s * 512);
        short8 b = *(const short8*)(fbp + s * 512);
        acc = __builtin_amdgcn_mfma_f32_32x32x16_bf16(a, b, acc, 0, 0, 0);
      }
    } else {
      for (int s = 0; s < (D >> 4); s++) {
        short8 a = *(const short8*)(fa + s * 512);
        short8 b = *(const short8*)(fbp + s * 512);
        acc = __builtin_amdgcn_mfma_f32_32x32x16_bf16(a, b, acc, 0, 0, 0);
      }
    }

    // inline bandwidth: ns = ||sum x||^2 from colsum (butterfly -> all lanes)
    float ns = 0.f;
    for (int d = lane * 8; d < D; d += 512) {
      float4 u0 = *(const float4*)(colsum + (size_t)c * D + d);
      float4 u1 = *(const float4*)(colsum + (size_t)c * D + d + 4);
      ns += u0.x * u0.x + u0.y * u0.y + u0.z * u0.z + u0.w * u0.w +
            u1.x * u1.x + u1.y * u1.y + u1.z * u1.z + u1.w * u1.w;
    }
    for (int o = 32; o > 0; o >>= 1) ns += __shfl_xor(ns, o, 64);
    float nf = (float)n;
    float S1 = 2.f * nf * ssum[c] - 2.f * ns;   // == m @ Dmat @ m
    float bw = S1 / fmaxf(nf * nf - nf, 1.f);
    bw = (bw > 0.f) ? bw : 1.f;
    float inv0 = 4.f / bw;                      // 1 / (bw * 0.25)

    float sqk = sqc[off + kbase + l31];
    float sgk = sgnc[off + kbase + l31];
    bool kval = (kbase + l31) < n;
    float sqjv = sqc[off + jbase + l31];
    float sgjv = sgnc[off + jbase + l31];
    float contrib = 0.f;
    #pragma unroll
    for (int r = 0; r < 16; r++) {
      int m = (r & 3) + 8 * (r >> 2) + 4 * half;
      float sqj = __shfl(sqjv, m, 64);
      float sgj = __shfl(sgjv, m, 64);
      if (kval && (jbase + m) < n) {
        float d = fmaxf(sqj + sqk - 2.f * acc[r], 0.f);
        float s = inv0, kv = 0.f;
        #pragma unroll
        for (int q = 0; q < 5; q++) { kv += __expf(-d * s); s *= 0.5f; }
        contrib += sgj * sgk * kv;
      }
    }
    contrib *= wgt;
    for (int o = 32; o > 0; o >>= 1) contrib += __shfl_down(contrib, o, 64);
    if (lane == 0) atomicAdd(&losssum[c], contrib);
  }

  // last-block fold -> final scalar (one fence+atomic per BLOCK)
  __syncthreads();
  if (tid == 0) {
    __threadfence();
    int d = atomicAdd(done, 1);
    lastFlag = (d == (int)gridDim.x - 1);
  }
  __syncthreads();
  if (lastFlag && tid < 64) {
    int c = tid;
    float loss = 0.f, cv = 0.f;
    if (c < C && srccnt[c] > 0 && tgtcnt[c] > 0) {
      float nf = (float)cnt[c];
      loss = atomicAdd(&losssum[c], 0.f) / fmaxf(nf * nf, 1.f);  // coherent read
      cv = 1.f;
    }
    for (int o = 32; o > 0; o >>= 1) {
      loss += __shfl_down(loss, o, 64);
      cv   += __shfl_down(cv, o, 64);
    }
    if (tid == 0) out[0] = loss / fmaxf(cv, 1.f);
  }
}

extern "C" void kernel_launch(void* const* d_in, const int* in_sizes, int n_in,
                              void* d_out, int out_size, void* d_ws, size_t ws_size,
                              hipStream_t stream) {
  const float* source = (const float*)d_in[0];
  const float* target = (const float*)d_in[1];
  const int* slab     = (const int*)d_in[2];
  const float* tlabel = (const float*)d_in[3];
  const int* nsd_p    = (const int*)d_in[4];
  float* out = (float*)d_out;

  int S_total = in_sizes[2];
  int D = in_sizes[0] / S_total;   // 512
  int T = in_sizes[1] / D;         // 2048
  int C = in_sizes[3] / T;         // 31
  int NMAX = S_total + T;          // 6144; actual N read on device

  // workspace layout (4-byte words); zeroed-by-memset region first (tiny)
  int* ws = (int*)d_ws;
  int* alloc    = ws;                     // C  (doubles as final cnt)
  int* srccnt   = alloc + C;              // C
  int* tgtcnt   = srccnt + C;             // C
  float* ssum   = (float*)(tgtcnt + C);   // C
  float* losssum = ssum + C;              // C
  int* done     = (int*)(losssum + C);    // 8
  float* colsum = (float*)(done + 8);     // C*D  (zeroed by memset too)
  int zwords    = 5 * C + 8 + C * D;

  float* sqc    = (float*)(ws + zwords);        // C*RCAP
  float* sgnc   = sqc + (size_t)C * RCAP;       // C*RCAP
  size_t words_used = (size_t)zwords + 2 * (size_t)C * RCAP;
  size_t fw = (words_used + 63) & ~(size_t)63;  // 256B-align fragbuf
  unsigned short* fragbuf = (unsigned short*)(ws + fw);  // C*RCAP*D bf16 (~195MB)

  hipMemsetAsync(d_ws, 0, (size_t)zwords * sizeof(int), stream);

  k_fused<<<NMAX / 64, 256, 0, stream>>>(source, target, slab, tlabel, nsd_p,
                                         alloc, srccnt, tgtcnt, ssum,
                                         fragbuf, sqc, sgnc,
                                         S_total, T, D, C);
  k_colsum<<<dim3(C, RCHUNK), 256, 0, stream>>>(fragbuf, alloc, colsum, D);
  k_pairs<<<208, 256, 0, stream>>>(fragbuf, sqc, sgnc, alloc, srccnt, tgtcnt,
                                   ssum, colsum, losssum, done, out, D, C);
}